// Round 4
// baseline (231.623 us; speedup 1.0000x reference)
//
#include <hip/hip_runtime.h>
#include <math.h>

#define BATCH 4
#define NPTS 8192
#define TPB 256
#define RPT 8                              // rows per thread
#define ROWS_PER_BLOCK (TPB * RPT)         // 2048
#define ROW_TILES (NPTS / ROWS_PER_BLOCK)  // 4
#define SEGS 32                            // column segments per row
#define COLS_PER_SEG (NPTS / SEGS)         // 256 == TPB (one staging round)
#define NGROUPS (2 * BATCH * ROW_TILES)    // 32 (dir,b,rowTile) groups
#define POISON 0xAAAAAAAAu                 // harness ws poison pattern

// ws layout: [NGROUPS][SEGS][ROWS_PER_BLOCK] partial mins (8 MB),
// then 32 group counters, 32 group sums, 1 global counter.
#define PART_BYTES ((size_t)NGROUPS * SEGS * ROWS_PER_BLOCK * 4)
#define CNT_OFF PART_BYTES
#define SUM_OFF (PART_BYTES + 128)
#define GCNT_OFF (PART_BYTES + 256)

typedef float v2f __attribute__((ext_vector_type(2)));
typedef float v4f __attribute__((ext_vector_type(4)));

// Packed fp32 FMA: 2 (row,col) dot-product steps per instruction.
#define PKFMA_NEW(t, a, b, c) \
  asm("v_pk_fma_f32 %0, %1, %2, %3" : "=v"(t) : "v"(a), "v"(b), "v"(c))
#define PKFMA(t, a, b) \
  asm("v_pk_fma_f32 %0, %1, %2, %0" : "+v"(t) : "v"(a), "v"(b))
#define MIN3(mn, ta, tb) \
  asm("v_min3_f32 %0, %0, %1, %2" : "+v"(mn) : "v"(ta), "v"(tb))

// One row x one column-pair: 3 pk_fma + 1 min3 = 4 instrs / 2 pairs.
#define ROWP(r, y0, y1, y2, yq)      \
  do {                               \
    v2f t;                           \
    PKFMA_NEW(t, xp##r##0, y0, yq);  \
    PKFMA(t, xp##r##1, y1);          \
    PKFMA(t, xp##r##2, y2);          \
    float tl = t.x, th = t.y;        \
    MIN3(mn##r, tl, th);             \
  } while (0)

#define LOADX(i, off)                                                   \
  const float* p##i = rows + ((size_t)(rowGlobal + (off) + tid)) * 3;   \
  const float x##i##0 = p##i[0], x##i##1 = p##i[1], x##i##2 = p##i[2];  \
  const v2f xp##i##0 = {x##i##0, x##i##0};                              \
  const v2f xp##i##1 = {x##i##1, x##i##1};                              \
  const v2f xp##i##2 = {x##i##2, x##i##2};                              \
  const float n##i =                                                    \
      x##i##0 * x##i##0 + x##i##1 * x##i##1 + x##i##2 * x##i##2;        \
  float mn##i = INFINITY;

// Single fused kernel. grid = (ROW_TILES*SEGS, BATCH, 2) = 1024 blocks
// (4 blocks/CU, 4 waves/SIMD). Each block: partial row-mins for its
// (dir,b,rowTile,seg); last-arriving block of each 32-block group does the
// cross-seg min + sqrt + sum; last group leader writes out[0]. Counter
// initial value is the harness's documented 0xAA ws poison; the mod-SEGS
// test stays correct even across multiple launches without re-poisoning.
__global__ __launch_bounds__(TPB, 4) void chamfer_fused(
    const float* __restrict__ pred, const float* __restrict__ label,
    float* __restrict__ ws_f, float* __restrict__ out) {
  const int tid = threadIdx.x;
  const int seg = blockIdx.x & (SEGS - 1);
  const int rowTile = blockIdx.x >> 5;
  const int b = blockIdx.y;
  const int dir = blockIdx.z;
  const int g = (dir * BATCH + b) * ROW_TILES + rowTile;
  const float* __restrict__ rows = (dir == 0) ? pred : label;
  const float* __restrict__ cols = (dir == 0) ? label : pred;

  __shared__ __align__(16) float sm0[COLS_PER_SEG];  // -2*y0
  __shared__ __align__(16) float sm1[COLS_PER_SEG];  // -2*y1
  __shared__ __align__(16) float sm2[COLS_PER_SEG];  // -2*y2
  __shared__ __align__(16) float sq[COLS_PER_SEG];   // y^2
  __shared__ float ssum[4];
  __shared__ unsigned sFlag;

  // Stage this segment's 256 columns as SoA (so col-pairs are VGPR pairs).
  {
    const float* q = cols + ((size_t)(b * NPTS + seg * COLS_PER_SEG + tid)) * 3;
    const float y0 = q[0], y1 = q[1], y2 = q[2];
    sm0[tid] = -2.0f * y0;
    sm1[tid] = -2.0f * y1;
    sm2[tid] = -2.0f * y2;
    sq[tid] = y0 * y0 + y1 * y1 + y2 * y2;
  }

  const int rowGlobal = b * NPTS + rowTile * ROWS_PER_BLOCK;
  LOADX(0, 0 * TPB)
  LOADX(1, 1 * TPB)
  LOADX(2, 2 * TPB)
  LOADX(3, 3 * TPB)
  LOADX(4, 4 * TPB)
  LOADX(5, 5 * TPB)
  LOADX(6, 6 * TPB)
  LOADX(7, 7 * TPB)

  __syncthreads();

#pragma unroll 2
  for (int l = 0; l < COLS_PER_SEG; l += 4) {
    const v4f a0 = *(const v4f*)&sm0[l];
    const v4f a1 = *(const v4f*)&sm1[l];
    const v4f a2 = *(const v4f*)&sm2[l];
    const v4f a3 = *(const v4f*)&sq[l];
    const v2f y0l = a0.lo, y1l = a1.lo, y2l = a2.lo, yql = a3.lo;
    ROWP(0, y0l, y1l, y2l, yql);
    ROWP(1, y0l, y1l, y2l, yql);
    ROWP(2, y0l, y1l, y2l, yql);
    ROWP(3, y0l, y1l, y2l, yql);
    ROWP(4, y0l, y1l, y2l, yql);
    ROWP(5, y0l, y1l, y2l, yql);
    ROWP(6, y0l, y1l, y2l, yql);
    ROWP(7, y0l, y1l, y2l, yql);
    const v2f y0h = a0.hi, y1h = a1.hi, y2h = a2.hi, yqh = a3.hi;
    ROWP(0, y0h, y1h, y2h, yqh);
    ROWP(1, y0h, y1h, y2h, yqh);
    ROWP(2, y0h, y1h, y2h, yqh);
    ROWP(3, y0h, y1h, y2h, yqh);
    ROWP(4, y0h, y1h, y2h, yqh);
    ROWP(5, y0h, y1h, y2h, yqh);
    ROWP(6, y0h, y1h, y2h, yqh);
    ROWP(7, y0h, y1h, y2h, yqh);
  }

  // Write the 8 partial row-mins for this (group, seg).
  float* wsl = ws_f + ((size_t)g * SEGS + seg) * ROWS_PER_BLOCK + tid;
  wsl[0 * TPB] = n0 + mn0;
  wsl[1 * TPB] = n1 + mn1;
  wsl[2 * TPB] = n2 + mn2;
  wsl[3 * TPB] = n3 + mn3;
  wsl[4 * TPB] = n4 + mn4;
  wsl[5 * TPB] = n5 + mn5;
  wsl[6 * TPB] = n6 + mn6;
  wsl[7 * TPB] = n7 + mn7;

  __threadfence();  // make partials device-visible before the count
  __syncthreads();  // also drains each wave's stores (vmcnt 0 at barrier)
  if (tid == 0) {
    unsigned* cnts = (unsigned*)((char*)ws_f + CNT_OFF);
    unsigned old = __hip_atomic_fetch_add(&cnts[g], 1u, __ATOMIC_ACQ_REL,
                                          __HIP_MEMORY_SCOPE_AGENT);
    sFlag = ((old - POISON) % SEGS == SEGS - 1u);
  }
  __syncthreads();
  if (!sFlag) return;

  // Leader block for group g: min over SEGS, sqrt, mean-scale, block sum.
  __threadfence();
  const float* gp = ws_f + (size_t)g * SEGS * ROWS_PER_BLOCK;
  float lsum = 0.0f;
#pragma unroll
  for (int k = 0; k < RPT; ++k) {
    const int r = k * TPB + tid;
    float m = INFINITY;
#pragma unroll
    for (int s = 0; s < SEGS; ++s) {
      const float v = __hip_atomic_load(&gp[s * ROWS_PER_BLOCK + r],
                                        __ATOMIC_RELAXED,
                                        __HIP_MEMORY_SCOPE_AGENT);
      m = fminf(m, v);
    }
    lsum += sqrtf(fmaxf(m, 0.0f));
  }
  lsum *= (1.0f / (float)(BATCH * NPTS));
  for (int off = 32; off > 0; off >>= 1) lsum += __shfl_down(lsum, off, 64);
  if ((tid & 63) == 0) ssum[tid >> 6] = lsum;
  __syncthreads();
  if (tid == 0) {
    const float gsum = ssum[0] + ssum[1] + ssum[2] + ssum[3];
    float* sums = (float*)((char*)ws_f + SUM_OFF);
    __hip_atomic_store(&sums[g], gsum, __ATOMIC_RELAXED,
                       __HIP_MEMORY_SCOPE_AGENT);
    unsigned* gcnt = (unsigned*)((char*)ws_f + GCNT_OFF);
    const unsigned o2 = __hip_atomic_fetch_add(gcnt, 1u, __ATOMIC_ACQ_REL,
                                               __HIP_MEMORY_SCOPE_AGENT);
    if ((o2 - POISON) % NGROUPS == NGROUPS - 1u) {
      float tot = 0.0f;
      for (int q = 0; q < NGROUPS; ++q)
        tot += __hip_atomic_load(&sums[q], __ATOMIC_RELAXED,
                                 __HIP_MEMORY_SCOPE_AGENT);
      out[0] = tot;
    }
  }
}

extern "C" void kernel_launch(void* const* d_in, const int* in_sizes, int n_in,
                              void* d_out, int out_size, void* d_ws,
                              size_t ws_size, hipStream_t stream) {
  const float* pred = (const float*)d_in[0];
  const float* label = (const float*)d_in[1];
  float* out = (float*)d_out;
  float* ws = (float*)d_ws;
  // needs PART_BYTES + 512 bytes of ws (8.0 MB); harness provides ~256 MB.
  dim3 grid(ROW_TILES * SEGS, BATCH, 2);
  chamfer_fused<<<grid, TPB, 0, stream>>>(pred, label, ws, out);
}

// Round 5
// 101.696 us; speedup vs baseline: 2.2776x; 2.2776x over previous
//
#include <hip/hip_runtime.h>
#include <math.h>

#define BATCH 4
#define NPTS 8192
#define TPB 256
#define RPT 16                             // rows per thread (2 rows share a coord reg-pair)
#define ROWS_PER_BLOCK (TPB * RPT)         // 4096
#define ROW_TILES (NPTS / ROWS_PER_BLOCK)  // 2
#define SEGS 32                            // column segments
#define COLS_PER_SEG (NPTS / SEGS)         // 256 == TPB: one staging round
#define NGROUPS (2 * BATCH * ROW_TILES)    // 16

typedef float v2f __attribute__((ext_vector_type(2)));
typedef float v4f __attribute__((ext_vector_type(4)));

// VOP3P packed fp32 FMA with op_sel broadcast of ONE 32-bit half of src0 to
// both lanes -> two rows share one coordinate register pair (R4's v2f
// broadcast needed 8 regs/row -> VGPR=56 alloc + scratch spills; this is
// 5 regs/row). [0]/[0] = both halves read src0.lo; [1]/[1] = src0.hi --
// invariant to the op_sel/op_sel_hi lo/hi-result convention.
#define PK_NEW_L(t, xp, y, c)                                        \
  asm("v_pk_fma_f32 %0, %1, %2, %3 op_sel:[0,0,0] op_sel_hi:[0,1,1]" \
      : "=v"(t) : "v"(xp), "v"(y), "v"(c))
#define PK_ACC_L(t, xp, y)                                           \
  asm("v_pk_fma_f32 %0, %1, %2, %0 op_sel:[0,0,0] op_sel_hi:[0,1,1]" \
      : "+v"(t) : "v"(xp), "v"(y))
#define PK_NEW_H(t, xp, y, c)                                        \
  asm("v_pk_fma_f32 %0, %1, %2, %3 op_sel:[1,0,0] op_sel_hi:[1,1,1]" \
      : "=v"(t) : "v"(xp), "v"(y), "v"(c))
#define PK_ACC_H(t, xp, y)                                           \
  asm("v_pk_fma_f32 %0, %1, %2, %0 op_sel:[1,0,0] op_sel_hi:[1,1,1]" \
      : "+v"(t) : "v"(xp), "v"(y))
#define MIN3(mn, ta, tb) \
  asm("v_min3_f32 %0, %0, %1, %2" : "+v"(mn) : "v"(ta), "v"(tb))

// Two rows (sharing xp regs) x two columns: 6 pk_fma + 2 min3 per 4 pairs.
#define ROWPAIR(i, y0, y1, y2, yq)   \
  do {                               \
    v2f tA, tB;                      \
    PK_NEW_L(tA, xp##i##0, y0, yq);  \
    PK_ACC_L(tA, xp##i##1, y1);      \
    PK_ACC_L(tA, xp##i##2, y2);      \
    float tal = tA.x, tah = tA.y;    \
    MIN3(mnA##i, tal, tah);          \
    PK_NEW_H(tB, xp##i##0, y0, yq);  \
    PK_ACC_H(tB, xp##i##1, y1);      \
    PK_ACC_H(tB, xp##i##2, y2);      \
    float tbl = tB.x, tbh = tB.y;    \
    MIN3(mnB##i, tbl, tbh);          \
  } while (0)

#define LOADX2(i)                                                              \
  const float* pA##i =                                                         \
      rows + ((size_t)(rowGlobal + (2 * (i)) * TPB + tid)) * 3;                \
  const float* pB##i =                                                         \
      rows + ((size_t)(rowGlobal + (2 * (i) + 1) * TPB + tid)) * 3;            \
  const float aA##i##0 = pA##i[0], aA##i##1 = pA##i[1], aA##i##2 = pA##i[2];   \
  const float aB##i##0 = pB##i[0], aB##i##1 = pB##i[1], aB##i##2 = pB##i[2];   \
  const v2f xp##i##0 = {aA##i##0, aB##i##0};                                   \
  const v2f xp##i##1 = {aA##i##1, aB##i##1};                                   \
  const v2f xp##i##2 = {aA##i##2, aB##i##2};                                   \
  const float nA##i =                                                          \
      aA##i##0 * aA##i##0 + aA##i##1 * aA##i##1 + aA##i##2 * aA##i##2;         \
  const float nB##i =                                                          \
      aB##i##0 * aB##i##0 + aB##i##1 * aB##i##1 + aB##i##2 * aB##i##2;         \
  float mnA##i = INFINITY, mnB##i = INFINITY;

// Kernel 1: partial row-mins. grid = (ROW_TILES*SEGS, BATCH, 2) = 512
// blocks = 2 blocks/CU, 8 waves/CU. launch_bounds(256,2) -> VGPR cap 256
// so the allocator keeps ~110 live regs without spilling (R4 lesson).
// No fences/agent atomics: the kernel boundary provides coherence.
__global__ __launch_bounds__(TPB, 2) void chamfer_partial(
    const float* __restrict__ pred, const float* __restrict__ label,
    float* __restrict__ ws, float* __restrict__ out) {
  const int tid = threadIdx.x;
  const int seg = blockIdx.x & (SEGS - 1);
  const int rowTile = blockIdx.x >> 5;
  const int b = blockIdx.y;
  const int dir = blockIdx.z;
  const int g = (dir * BATCH + b) * ROW_TILES + rowTile;
  const float* __restrict__ rows = (dir == 0) ? pred : label;
  const float* __restrict__ cols = (dir == 0) ? label : pred;

  // Zero the output scalar (stream-ordered before chamfer_reduce's atomics).
  if (blockIdx.x == 0 && b == 0 && dir == 0 && tid == 0) out[0] = 0.0f;

  __shared__ __align__(16) float sm0[COLS_PER_SEG];  // -2*y0
  __shared__ __align__(16) float sm1[COLS_PER_SEG];  // -2*y1
  __shared__ __align__(16) float sm2[COLS_PER_SEG];  // -2*y2
  __shared__ __align__(16) float sq[COLS_PER_SEG];   // y^2

  {
    const float* q =
        cols + ((size_t)(b * NPTS + seg * COLS_PER_SEG + tid)) * 3;
    const float y0 = q[0], y1 = q[1], y2 = q[2];
    sm0[tid] = -2.0f * y0;
    sm1[tid] = -2.0f * y1;
    sm2[tid] = -2.0f * y2;
    sq[tid] = y0 * y0 + y1 * y1 + y2 * y2;
  }

  const int rowGlobal = b * NPTS + rowTile * ROWS_PER_BLOCK;
  LOADX2(0) LOADX2(1) LOADX2(2) LOADX2(3)
  LOADX2(4) LOADX2(5) LOADX2(6) LOADX2(7)

  __syncthreads();

#pragma unroll 2
  for (int l = 0; l < COLS_PER_SEG; l += 4) {
    const v4f a0 = *(const v4f*)&sm0[l];
    const v4f a1 = *(const v4f*)&sm1[l];
    const v4f a2 = *(const v4f*)&sm2[l];
    const v4f a3 = *(const v4f*)&sq[l];
    {
      const v2f y0 = a0.lo, y1 = a1.lo, y2 = a2.lo, yq = a3.lo;
      ROWPAIR(0, y0, y1, y2, yq);
      ROWPAIR(1, y0, y1, y2, yq);
      ROWPAIR(2, y0, y1, y2, yq);
      ROWPAIR(3, y0, y1, y2, yq);
      ROWPAIR(4, y0, y1, y2, yq);
      ROWPAIR(5, y0, y1, y2, yq);
      ROWPAIR(6, y0, y1, y2, yq);
      ROWPAIR(7, y0, y1, y2, yq);
    }
    {
      const v2f y0 = a0.hi, y1 = a1.hi, y2 = a2.hi, yq = a3.hi;
      ROWPAIR(0, y0, y1, y2, yq);
      ROWPAIR(1, y0, y1, y2, yq);
      ROWPAIR(2, y0, y1, y2, yq);
      ROWPAIR(3, y0, y1, y2, yq);
      ROWPAIR(4, y0, y1, y2, yq);
      ROWPAIR(5, y0, y1, y2, yq);
      ROWPAIR(6, y0, y1, y2, yq);
      ROWPAIR(7, y0, y1, y2, yq);
    }
  }

  float* wsl = ws + ((size_t)g * SEGS + seg) * ROWS_PER_BLOCK + tid;
#define STORE2(i)                                   \
  wsl[(2 * (i)) * TPB] = nA##i + mnA##i;            \
  wsl[(2 * (i) + 1) * TPB] = nB##i + mnB##i;
  STORE2(0) STORE2(1) STORE2(2) STORE2(3)
  STORE2(4) STORE2(5) STORE2(6) STORE2(7)
#undef STORE2
}

// Kernel 2: per row, min over SEGS partials (unrolled independent loads),
// clamp, sqrt, scale, block-reduce, one atomicAdd per block.
__global__ __launch_bounds__(256) void chamfer_reduce(
    const float* __restrict__ ws, float* __restrict__ out) {
  const int r = blockIdx.x * 256 + threadIdx.x;  // 0..65535 global row
  const int db = r >> 13;                        // dir*BATCH+b
  const int rowInB = r & (NPTS - 1);
  const int rowTile = rowInB >> 12;              // / ROWS_PER_BLOCK
  const int rloc = rowInB & (ROWS_PER_BLOCK - 1);
  const int g = db * ROW_TILES + rowTile;
  const float* p = ws + (size_t)g * SEGS * ROWS_PER_BLOCK + rloc;
  float m = INFINITY;
#pragma unroll
  for (int s = 0; s < SEGS; ++s) m = fminf(m, p[(size_t)s * ROWS_PER_BLOCK]);
  float sum = sqrtf(fmaxf(m, 0.0f)) * (1.0f / (float)(BATCH * NPTS));
  for (int off = 32; off > 0; off >>= 1) sum += __shfl_down(sum, off, 64);
  __shared__ float ssum[4];
  if ((threadIdx.x & 63) == 0) ssum[threadIdx.x >> 6] = sum;
  __syncthreads();
  if (threadIdx.x == 0) atomicAdd(out, ssum[0] + ssum[1] + ssum[2] + ssum[3]);
}

extern "C" void kernel_launch(void* const* d_in, const int* in_sizes, int n_in,
                              void* d_out, int out_size, void* d_ws,
                              size_t ws_size, hipStream_t stream) {
  const float* pred = (const float*)d_in[0];
  const float* label = (const float*)d_in[1];
  float* out = (float*)d_out;
  float* ws = (float*)d_ws;
  // ws use: NGROUPS*SEGS*ROWS_PER_BLOCK floats = 8 MB (harness gives ~256 MB).
  dim3 grid1(ROW_TILES * SEGS, BATCH, 2);
  chamfer_partial<<<grid1, TPB, 0, stream>>>(pred, label, ws, out);
  chamfer_reduce<<<NPTS * 2 * BATCH / 256, 256, 0, stream>>>(ws, out);
}